// Round 1
// baseline (1593.290 us; speedup 1.0000x reference)
//
#include <hip/hip_runtime.h>
#include <math.h>

#define EMB_K   768
#define NH      96
#define SEQLEN  2048
#define NBATCH  16
#define MROWS   (NBATCH * SEQLEN)   // 32768

// ---------------------------------------------------------------------------
// Phase 1: QKV projection GEMM. M=32768, K=768, N=96; blockIdx.y picks W/out.
// Block 384 threads; tile 64(M) x 96(N), BK=32; per-thread 4x4 register tile.
// ---------------------------------------------------------------------------
__global__ __launch_bounds__(384) void qkv_kernel(
    const float* __restrict__ x,
    const float* __restrict__ Wq,
    const float* __restrict__ Wk,
    const float* __restrict__ Wv,
    float* __restrict__ qkv)
{
    // pad 34: row stride 34 -> float2 reads 8B-aligned, banks (2r+c)%32
    __shared__ float Xs[64][34];
    __shared__ float Ws[32][96];

    const float* W = (blockIdx.y == 0) ? Wq : ((blockIdx.y == 1) ? Wk : Wv);
    float* outp = qkv + (size_t)blockIdx.y * (size_t)MROWS * NH;

    const int m0  = blockIdx.x * 64;
    const int tid = threadIdx.x;
    const int tm  = tid / 24;   // 0..15 -> rows tm*4 .. tm*4+3
    const int tn  = tid % 24;   // 0..23 -> cols tn*4 .. tn*4+3

    float acc[4][4];
    #pragma unroll
    for (int i = 0; i < 4; ++i)
        #pragma unroll
        for (int j = 0; j < 4; ++j)
            acc[i][j] = 0.0f;

    for (int k0 = 0; k0 < EMB_K; k0 += 32) {
        for (int i = tid; i < 64 * 32; i += 384) {
            int r = i >> 5, c = i & 31;
            Xs[r][c] = x[(size_t)(m0 + r) * EMB_K + (k0 + c)];
        }
        for (int i = tid; i < 32 * 96; i += 384) {
            int r = i / 96, c = i - r * 96;
            Ws[r][c] = W[(size_t)(k0 + r) * NH + c];
        }
        __syncthreads();

        #pragma unroll
        for (int kk = 0; kk < 32; kk += 2) {
            float2 a[4];
            #pragma unroll
            for (int i = 0; i < 4; ++i)
                a[i] = *(const float2*)&Xs[tm * 4 + i][kk];
            float4 b0 = *(const float4*)&Ws[kk][tn * 4];
            float4 b1 = *(const float4*)&Ws[kk + 1][tn * 4];
            #pragma unroll
            for (int i = 0; i < 4; ++i) {
                acc[i][0] += a[i].x * b0.x + a[i].y * b1.x;
                acc[i][1] += a[i].x * b0.y + a[i].y * b1.y;
                acc[i][2] += a[i].x * b0.z + a[i].y * b1.z;
                acc[i][3] += a[i].x * b0.w + a[i].y * b1.w;
            }
        }
        __syncthreads();
    }

    #pragma unroll
    for (int i = 0; i < 4; ++i) {
        float4 o = make_float4(acc[i][0], acc[i][1], acc[i][2], acc[i][3]);
        *(float4*)&outp[(size_t)(m0 + tm * 4 + i) * NH + tn * 4] = o;
    }
}

// ---------------------------------------------------------------------------
// Phase 2: causal flash attention, fp32.
// One block per (batch, 64-row Q tile); KV tiles of 32.
// Threads 256: tm=tid>>4 (4 Q-rows each), tn=tid&15.
// S-GEMM per-thread tile: 4 rows x 2 cols. PV: 4 rows x 6 out-cols.
// LDS: QsT[96][68] + KsT[96][34] + Vs[32][98] + Ps[64][34] = 59 KB.
// ---------------------------------------------------------------------------
__global__ __launch_bounds__(256) void attn_kernel(
    const float* __restrict__ qkv,
    float* __restrict__ out)
{
    __shared__ float QsT[96][68];  // [head_dim][q_row], padded for f4 align
    __shared__ float KsT[96][34];  // [head_dim][kv_row]
    __shared__ float Vs[32][98];   // [kv_row][head_dim]
    __shared__ float Ps[64][34];   // [q_row][kv_col]

    const int bid = blockIdx.x;
    const int b   = bid & 15;
    const int rr_ = bid >> 4;                      // 0..31
    const int qt  = (rr_ < 16) ? (2 * rr_) : (63 - 2 * rr_);  // load-balance swizzle
    const int q0  = qt * 64;

    const float* qp = qkv + (size_t)b * SEQLEN * NH;
    const float* kp = qkv + (size_t)MROWS * NH + (size_t)b * SEQLEN * NH;
    const float* vp = qkv + (size_t)2 * MROWS * NH + (size_t)b * SEQLEN * NH;

    const int tid = threadIdx.x;
    const int tm  = tid >> 4;   // 0..15
    const int tn  = tid & 15;   // 0..15

    // stage Q tile transposed (once per block)
    for (int idx = tid; idx < 64 * 96; idx += 256) {
        int r = idx / 96, c = idx - r * 96;
        QsT[c][r] = qp[(size_t)(q0 + r) * NH + c];
    }

    float m_run[4], l_run[4], Oacc[4][6];
    #pragma unroll
    for (int i = 0; i < 4; ++i) {
        m_run[i] = -INFINITY;
        l_run[i] = 0.0f;
        #pragma unroll
        for (int j = 0; j < 6; ++j) Oacc[i][j] = 0.0f;
    }

    // softmax in exp2 domain: fold head_size^-0.5 * log2(e) into the score scale
    const float sscale = 0.10206207261596575f * 1.4426950408889634f;

    const int ntiles = 2 * (qt + 1);
    for (int t = 0; t < ntiles; ++t) {
        const int k0 = t * 32;
        __syncthreads();  // previous tile's PV reads done before overwriting LDS
        for (int idx = tid; idx < 32 * 96; idx += 256) {
            int r = idx / 96, c = idx - r * 96;
            KsT[c][r] = kp[(size_t)(k0 + r) * NH + c];
            Vs[r][c]  = vp[(size_t)(k0 + r) * NH + c];
        }
        __syncthreads();

        // S = Q . K^T  (over 96 head dims)
        float sacc[4][2];
        #pragma unroll
        for (int i = 0; i < 4; ++i) { sacc[i][0] = 0.0f; sacc[i][1] = 0.0f; }
        #pragma unroll 4
        for (int h = 0; h < 96; ++h) {
            float4 a4 = *(const float4*)&QsT[h][tm * 4];
            float2 b2 = *(const float2*)&KsT[h][tn * 2];
            float aa[4] = {a4.x, a4.y, a4.z, a4.w};
            #pragma unroll
            for (int i = 0; i < 4; ++i) {
                sacc[i][0] += aa[i] * b2.x;
                sacc[i][1] += aa[i] * b2.y;
            }
        }

        // scale + causal mask
        float s2[4][2];
        #pragma unroll
        for (int i = 0; i < 4; ++i) {
            s2[i][0] = sacc[i][0] * sscale;
            s2[i][1] = sacc[i][1] * sscale;
        }
        if (k0 + 31 > q0) {
            #pragma unroll
            for (int i = 0; i < 4; ++i) {
                int qg = q0 + tm * 4 + i;
                #pragma unroll
                for (int j = 0; j < 2; ++j) {
                    int kg = k0 + tn * 2 + j;
                    if (kg > qg) s2[i][j] = -1e20f;
                }
            }
        }

        // per-row tile max across the 16 lanes sharing tm
        float mt[4];
        #pragma unroll
        for (int i = 0; i < 4; ++i) mt[i] = fmaxf(s2[i][0], s2[i][1]);
        #pragma unroll
        for (int off = 1; off < 16; off <<= 1) {
            #pragma unroll
            for (int i = 0; i < 4; ++i)
                mt[i] = fmaxf(mt[i], __shfl_xor(mt[i], off));
        }

        float alpha[4];
        #pragma unroll
        for (int i = 0; i < 4; ++i) {
            float mn = fmaxf(m_run[i], mt[i]);
            alpha[i] = exp2f(m_run[i] - mn);  // -inf - finite -> 0 on first tile
            m_run[i] = mn;
        }

        float p[4][2], rs[4];
        #pragma unroll
        for (int i = 0; i < 4; ++i) {
            p[i][0] = exp2f(s2[i][0] - m_run[i]);
            p[i][1] = exp2f(s2[i][1] - m_run[i]);
            rs[i] = p[i][0] + p[i][1];
        }
        #pragma unroll
        for (int off = 1; off < 16; off <<= 1) {
            #pragma unroll
            for (int i = 0; i < 4; ++i)
                rs[i] += __shfl_xor(rs[i], off);
        }
        #pragma unroll
        for (int i = 0; i < 4; ++i) {
            l_run[i] = l_run[i] * alpha[i] + rs[i];
            #pragma unroll
            for (int j = 0; j < 6; ++j) Oacc[i][j] *= alpha[i];
        }

        // P -> LDS for the PV GEMM
        #pragma unroll
        for (int i = 0; i < 4; ++i) {
            float2 pw = make_float2(p[i][0], p[i][1]);
            *(float2*)&Ps[tm * 4 + i][tn * 2] = pw;
        }
        __syncthreads();

        // O += P . V
        #pragma unroll 2
        for (int c = 0; c < 32; ++c) {
            float av[4];
            #pragma unroll
            for (int i = 0; i < 4; ++i) av[i] = Ps[tm * 4 + i][c];
            float2 t0 = *(const float2*)&Vs[c][tn * 6];
            float2 t1 = *(const float2*)&Vs[c][tn * 6 + 2];
            float2 t2 = *(const float2*)&Vs[c][tn * 6 + 4];
            float vv[6] = {t0.x, t0.y, t1.x, t1.y, t2.x, t2.y};
            #pragma unroll
            for (int i = 0; i < 4; ++i)
                #pragma unroll
                for (int j = 0; j < 6; ++j)
                    Oacc[i][j] += av[i] * vv[j];
        }
    }

    // epilogue: normalize and store
    #pragma unroll
    for (int i = 0; i < 4; ++i) {
        float inv = 1.0f / l_run[i];
        float* orow = out + ((size_t)b * SEQLEN + q0 + tm * 4 + i) * NH + tn * 6;
        *(float2*)(orow)     = make_float2(Oacc[i][0] * inv, Oacc[i][1] * inv);
        *(float2*)(orow + 2) = make_float2(Oacc[i][2] * inv, Oacc[i][3] * inv);
        *(float2*)(orow + 4) = make_float2(Oacc[i][4] * inv, Oacc[i][5] * inv);
    }
}

// ---------------------------------------------------------------------------
extern "C" void kernel_launch(void* const* d_in, const int* in_sizes, int n_in,
                              void* d_out, int out_size, void* d_ws, size_t ws_size,
                              hipStream_t stream)
{
    (void)in_sizes; (void)n_in; (void)out_size; (void)ws_size;
    const float* x  = (const float*)d_in[0];
    const float* Wq = (const float*)d_in[1];
    const float* Wk = (const float*)d_in[2];
    const float* Wv = (const float*)d_in[3];
    float* out = (float*)d_out;
    float* qkv = (float*)d_ws;   // 3 * 32768 * 96 floats = 37.7 MB

    dim3 g1(MROWS / 64, 3);
    qkv_kernel<<<g1, 384, 0, stream>>>(x, Wq, Wk, Wv, qkv);

    attn_kernel<<<dim3(512), 256, 0, stream>>>(qkv, out);
}

// Round 2
// 762.717 us; speedup vs baseline: 2.0890x; 2.0890x over previous
//
#include <hip/hip_runtime.h>
#include <math.h>

#define EMB_K   768
#define NH      96
#define SEQLEN  2048
#define NBATCH  16
#define MROWS   (NBATCH * SEQLEN)   // 32768

typedef __bf16 v8bf __attribute__((ext_vector_type(8)));
typedef float  v4f  __attribute__((ext_vector_type(4)));

// ---------------------------------------------------------------------------
// Pack Wq/Wk/Wv (fp32 [768][96]) into bf16 B-fragment order for
// mfma_f32_16x16x32_bf16:  B[k][n] with n = lane&15, k = (lane>>4)*8 + e.
// Layout: frag (w, s, j) at ((w*24 + s)*6 + j)*512 + lane*8 + e   (bf16 units)
//   w: 0..2 (Q/K/V), s: 0..23 (K-slice of 32), j: 0..5 (N-tile of 16)
// ---------------------------------------------------------------------------
__global__ __launch_bounds__(256) void pack_w(
    const float* __restrict__ Wq,
    const float* __restrict__ Wk,
    const float* __restrict__ Wv,
    __bf16* __restrict__ Wp)
{
    int t = blockIdx.x * 256 + threadIdx.x;          // one thread per (w,s,j,lane)
    if (t >= 3 * 24 * 6 * 64) return;
    int l  = t & 63;
    int fj = (t >> 6) % 6;
    int s  = ((t >> 6) / 6) % 24;
    int w  = (t >> 6) / (6 * 24);
    const float* W = (w == 0) ? Wq : ((w == 1) ? Wk : Wv);
    int n     = fj * 16 + (l & 15);
    int kbase = s * 32 + (l >> 4) * 8;
    __bf16 o[8];
    #pragma unroll
    for (int e = 0; e < 8; ++e)
        o[e] = (__bf16)W[(size_t)(kbase + e) * NH + n];
    *(v8bf*)(Wp + (size_t)t * 8) = *(v8bf*)o;
}

// ---------------------------------------------------------------------------
// QKV projection via bf16 MFMA. No LDS, no barriers.
// Grid: (M/128, 3). Block 256 thr = 4 waves; wave tile 32(M) x 96(N).
// Per K-slice (32): 2 A-frags (fp32 global -> cvt), 6 B-frags (packed), 12 MFMA.
// ---------------------------------------------------------------------------
__device__ inline v8bf cvt8(const float4& a, const float4& b)
{
    v8bf r;
    r[0] = (__bf16)a.x; r[1] = (__bf16)a.y; r[2] = (__bf16)a.z; r[3] = (__bf16)a.w;
    r[4] = (__bf16)b.x; r[5] = (__bf16)b.y; r[6] = (__bf16)b.z; r[7] = (__bf16)b.w;
    return r;
}

__global__ __launch_bounds__(256) void qkv_mfma(
    const float* __restrict__ x,
    const __bf16* __restrict__ Wp,
    float* __restrict__ qkv)
{
    const int w    = blockIdx.y;            // 0..2 selects Q/K/V
    const int m0   = blockIdx.x * 128;
    const int wave = threadIdx.x >> 6;      // 0..3
    const int lane = threadIdx.x & 63;
    const int mlow = lane & 15;
    const int kq   = lane >> 4;             // 0..3 -> k offset kq*8

    const int r0 = m0 + wave * 32;
    const float* xr0 = x + (size_t)(r0 + mlow) * EMB_K + kq * 8;
    const float* xr1 = xr0 + (size_t)16 * EMB_K;
    const __bf16* bp = Wp + ((size_t)w * 24 * 6) * 512 + (size_t)lane * 8;

    v4f acc[2][6];
    #pragma unroll
    for (int i = 0; i < 2; ++i)
        #pragma unroll
        for (int j = 0; j < 6; ++j)
            acc[i][j] = (v4f)0.0f;

    for (int s = 0; s < 24; ++s) {
        float4 a0lo = *(const float4*)(xr0 + s * 32);
        float4 a0hi = *(const float4*)(xr0 + s * 32 + 4);
        float4 a1lo = *(const float4*)(xr1 + s * 32);
        float4 a1hi = *(const float4*)(xr1 + s * 32 + 4);
        v8bf a0 = cvt8(a0lo, a0hi);
        v8bf a1 = cvt8(a1lo, a1hi);
        const __bf16* bs = bp + (size_t)s * 6 * 512;
        #pragma unroll
        for (int j = 0; j < 6; ++j) {
            v8bf bf = *(const v8bf*)(bs + (size_t)j * 512);
            acc[0][j] = __builtin_amdgcn_mfma_f32_16x16x32_bf16(a0, bf, acc[0][j], 0, 0, 0);
            acc[1][j] = __builtin_amdgcn_mfma_f32_16x16x32_bf16(a1, bf, acc[1][j], 0, 0, 0);
        }
    }

    // Epilogue: D row = (lane>>4)*4 + r, col = lane&15  (HW-verified layout)
    float* op = qkv + (size_t)w * MROWS * NH;
    #pragma unroll
    for (int i = 0; i < 2; ++i) {
        #pragma unroll
        for (int r = 0; r < 4; ++r) {
            int row = r0 + i * 16 + kq * 4 + r;
            #pragma unroll
            for (int j = 0; j < 6; ++j)
                op[(size_t)row * NH + j * 16 + mlow] = acc[i][j][r];
        }
    }
}

// ---------------------------------------------------------------------------
// Phase 2: causal flash attention, fp32 (unchanged this round).
// ---------------------------------------------------------------------------
__global__ __launch_bounds__(256) void attn_kernel(
    const float* __restrict__ qkv,
    float* __restrict__ out)
{
    __shared__ float QsT[96][68];
    __shared__ float KsT[96][34];
    __shared__ float Vs[32][98];
    __shared__ float Ps[64][34];

    const int bid = blockIdx.x;
    const int b   = bid & 15;
    const int rr_ = bid >> 4;
    const int qt  = (rr_ < 16) ? (2 * rr_) : (63 - 2 * rr_);
    const int q0  = qt * 64;

    const float* qp = qkv + (size_t)b * SEQLEN * NH;
    const float* kp = qkv + (size_t)MROWS * NH + (size_t)b * SEQLEN * NH;
    const float* vp = qkv + (size_t)2 * MROWS * NH + (size_t)b * SEQLEN * NH;

    const int tid = threadIdx.x;
    const int tm  = tid >> 4;
    const int tn  = tid & 15;

    for (int idx = tid; idx < 64 * 96; idx += 256) {
        int r = idx / 96, c = idx - r * 96;
        QsT[c][r] = qp[(size_t)(q0 + r) * NH + c];
    }

    float m_run[4], l_run[4], Oacc[4][6];
    #pragma unroll
    for (int i = 0; i < 4; ++i) {
        m_run[i] = -INFINITY;
        l_run[i] = 0.0f;
        #pragma unroll
        for (int j = 0; j < 6; ++j) Oacc[i][j] = 0.0f;
    }

    const float sscale = 0.10206207261596575f * 1.4426950408889634f;

    const int ntiles = 2 * (qt + 1);
    for (int t = 0; t < ntiles; ++t) {
        const int k0 = t * 32;
        __syncthreads();
        for (int idx = tid; idx < 32 * 96; idx += 256) {
            int r = idx / 96, c = idx - r * 96;
            KsT[c][r] = kp[(size_t)(k0 + r) * NH + c];
            Vs[r][c]  = vp[(size_t)(k0 + r) * NH + c];
        }
        __syncthreads();

        float sacc[4][2];
        #pragma unroll
        for (int i = 0; i < 4; ++i) { sacc[i][0] = 0.0f; sacc[i][1] = 0.0f; }
        #pragma unroll 4
        for (int h = 0; h < 96; ++h) {
            float4 a4 = *(const float4*)&QsT[h][tm * 4];
            float2 b2 = *(const float2*)&KsT[h][tn * 2];
            float aa[4] = {a4.x, a4.y, a4.z, a4.w};
            #pragma unroll
            for (int i = 0; i < 4; ++i) {
                sacc[i][0] += aa[i] * b2.x;
                sacc[i][1] += aa[i] * b2.y;
            }
        }

        float s2[4][2];
        #pragma unroll
        for (int i = 0; i < 4; ++i) {
            s2[i][0] = sacc[i][0] * sscale;
            s2[i][1] = sacc[i][1] * sscale;
        }
        if (k0 + 31 > q0) {
            #pragma unroll
            for (int i = 0; i < 4; ++i) {
                int qg = q0 + tm * 4 + i;
                #pragma unroll
                for (int j = 0; j < 2; ++j) {
                    int kg = k0 + tn * 2 + j;
                    if (kg > qg) s2[i][j] = -1e20f;
                }
            }
        }

        float mt[4];
        #pragma unroll
        for (int i = 0; i < 4; ++i) mt[i] = fmaxf(s2[i][0], s2[i][1]);
        #pragma unroll
        for (int off = 1; off < 16; off <<= 1) {
            #pragma unroll
            for (int i = 0; i < 4; ++i)
                mt[i] = fmaxf(mt[i], __shfl_xor(mt[i], off));
        }

        float alpha[4];
        #pragma unroll
        for (int i = 0; i < 4; ++i) {
            float mn = fmaxf(m_run[i], mt[i]);
            alpha[i] = exp2f(m_run[i] - mn);
            m_run[i] = mn;
        }

        float p[4][2], rs[4];
        #pragma unroll
        for (int i = 0; i < 4; ++i) {
            p[i][0] = exp2f(s2[i][0] - m_run[i]);
            p[i][1] = exp2f(s2[i][1] - m_run[i]);
            rs[i] = p[i][0] + p[i][1];
        }
        #pragma unroll
        for (int off = 1; off < 16; off <<= 1) {
            #pragma unroll
            for (int i = 0; i < 4; ++i)
                rs[i] += __shfl_xor(rs[i], off);
        }
        #pragma unroll
        for (int i = 0; i < 4; ++i) {
            l_run[i] = l_run[i] * alpha[i] + rs[i];
            #pragma unroll
            for (int j = 0; j < 6; ++j) Oacc[i][j] *= alpha[i];
        }

        #pragma unroll
        for (int i = 0; i < 4; ++i) {
            float2 pw = make_float2(p[i][0], p[i][1]);
            *(float2*)&Ps[tm * 4 + i][tn * 2] = pw;
        }
        __syncthreads();

        #pragma unroll 2
        for (int c = 0; c < 32; ++c) {
            float av[4];
            #pragma unroll
            for (int i = 0; i < 4; ++i) av[i] = Ps[tm * 4 + i][c];
            float2 t0 = *(const float2*)&Vs[c][tn * 6];
            float2 t1 = *(const float2*)&Vs[c][tn * 6 + 2];
            float2 t2 = *(const float2*)&Vs[c][tn * 6 + 4];
            float vv[6] = {t0.x, t0.y, t1.x, t1.y, t2.x, t2.y};
            #pragma unroll
            for (int i = 0; i < 4; ++i)
                #pragma unroll
                for (int j = 0; j < 6; ++j)
                    Oacc[i][j] += av[i] * vv[j];
        }
    }

    #pragma unroll
    for (int i = 0; i < 4; ++i) {
        float inv = 1.0f / l_run[i];
        float* orow = out + ((size_t)b * SEQLEN + q0 + tm * 4 + i) * NH + tn * 6;
        *(float2*)(orow)     = make_float2(Oacc[i][0] * inv, Oacc[i][1] * inv);
        *(float2*)(orow + 2) = make_float2(Oacc[i][2] * inv, Oacc[i][3] * inv);
        *(float2*)(orow + 4) = make_float2(Oacc[i][4] * inv, Oacc[i][5] * inv);
    }
}

// ---------------------------------------------------------------------------
extern "C" void kernel_launch(void* const* d_in, const int* in_sizes, int n_in,
                              void* d_out, int out_size, void* d_ws, size_t ws_size,
                              hipStream_t stream)
{
    (void)in_sizes; (void)n_in; (void)out_size; (void)ws_size;
    const float* x  = (const float*)d_in[0];
    const float* Wq = (const float*)d_in[1];
    const float* Wk = (const float*)d_in[2];
    const float* Wv = (const float*)d_in[3];
    float* out = (float*)d_out;

    float*  qkv = (float*)d_ws;                            // 37.75 MB
    __bf16* Wp  = (__bf16*)((char*)d_ws + (size_t)3 * MROWS * NH * sizeof(float));

    pack_w<<<(3 * 24 * 6 * 64 + 255) / 256, 256, 0, stream>>>(Wq, Wk, Wv, Wp);

    dim3 g1(MROWS / 128, 3);
    qkv_mfma<<<g1, 256, 0, stream>>>(x, Wp, qkv);

    attn_kernel<<<dim3(512), 256, 0, stream>>>(qkv, out);
}

// Round 3
// 397.200 us; speedup vs baseline: 4.0113x; 1.9202x over previous
//
#include <hip/hip_runtime.h>
#include <math.h>

#define EMB_K   768
#define NH      96
#define SEQLEN  2048
#define NBATCH  16
#define MROWS   (NBATCH * SEQLEN)   // 32768

typedef __bf16 v8bf __attribute__((ext_vector_type(8)));
typedef float  v4f  __attribute__((ext_vector_type(4)));

// ---------------------------------------------------------------------------
// Pack Wq/Wk/Wv (fp32 [768][96]) into bf16 B-fragment order for
// mfma_f32_16x16x32_bf16:  B[k][n], n = lane&15, k = (lane>>4)*8 + e.
// Frag (w, s, j) at ((w*24 + s)*6 + j)*512 + lane*8 + e  (bf16 units)
// ---------------------------------------------------------------------------
__global__ __launch_bounds__(256) void pack_w(
    const float* __restrict__ Wq,
    const float* __restrict__ Wk,
    const float* __restrict__ Wv,
    __bf16* __restrict__ Wp)
{
    int t = blockIdx.x * 256 + threadIdx.x;
    if (t >= 3 * 24 * 6 * 64) return;
    int l  = t & 63;
    int fj = (t >> 6) % 6;
    int s  = ((t >> 6) / 6) % 24;
    int w  = (t >> 6) / (6 * 24);
    const float* W = (w == 0) ? Wq : ((w == 1) ? Wk : Wv);
    int n     = fj * 16 + (l & 15);
    int kbase = s * 32 + (l >> 4) * 8;
    __bf16 o[8];
    #pragma unroll
    for (int e = 0; e < 8; ++e)
        o[e] = (__bf16)W[(size_t)(kbase + e) * NH + n];
    *(v8bf*)(Wp + (size_t)t * 8) = *(v8bf*)o;
}

__device__ inline v8bf cvt8(const float4& a, const float4& b)
{
    v8bf r;
    r[0] = (__bf16)a.x; r[1] = (__bf16)a.y; r[2] = (__bf16)a.z; r[3] = (__bf16)a.w;
    r[4] = (__bf16)b.x; r[5] = (__bf16)b.y; r[6] = (__bf16)b.z; r[7] = (__bf16)b.w;
    return r;
}

// ---------------------------------------------------------------------------
// Fused QKV: one pass over x, Q/K/V accumulated together.
// Grid 512 blocks (64 rows), 4 waves x 16 rows. Per K-slice: 1 A-frag, 18 MFMA.
// Q,K stored bf16 row-major [w][32768][96]; V stored TRANSPOSED vt[96][32768]
// via an LDS bounce so attention's PV B-fragments are contiguous loads.
// ---------------------------------------------------------------------------
__global__ __launch_bounds__(256) void qkv_fused(
    const float* __restrict__ x,
    const __bf16* __restrict__ Wp,
    __bf16* __restrict__ qk,
    __bf16* __restrict__ vt)
{
    __shared__ __bf16 VsT[96][72];

    const int wave = threadIdx.x >> 6;
    const int lane = threadIdx.x & 63;
    const int mlow = lane & 15;
    const int kq   = lane >> 4;
    const int m0   = blockIdx.x * 64;
    const int r0   = m0 + wave * 16;

    const float* xr = x + (size_t)(r0 + mlow) * EMB_K + kq * 8;
    const __bf16* bp = Wp + (size_t)lane * 8;

    v4f acc[3][6];
    #pragma unroll
    for (int w = 0; w < 3; ++w)
        #pragma unroll
        for (int j = 0; j < 6; ++j)
            acc[w][j] = (v4f)0.0f;

    for (int s = 0; s < 24; ++s) {
        float4 lo = *(const float4*)(xr + s * 32);
        float4 hi = *(const float4*)(xr + s * 32 + 4);
        v8bf a = cvt8(lo, hi);
        #pragma unroll
        for (int w = 0; w < 3; ++w)
            #pragma unroll
            for (int j = 0; j < 6; ++j) {
                v8bf bf = *(const v8bf*)(bp + ((size_t)(w * 24 + s) * 6 + j) * 512);
                acc[w][j] = __builtin_amdgcn_mfma_f32_16x16x32_bf16(a, bf, acc[w][j], 0, 0, 0);
            }
    }

    // Q, K: bf16 row-major.  C layout: row=(lane>>4)*4+r, col=lane&15.
    #pragma unroll
    for (int w = 0; w < 2; ++w) {
        __bf16* op = qk + (size_t)w * MROWS * NH;
        #pragma unroll
        for (int j = 0; j < 6; ++j)
            #pragma unroll
            for (int r = 0; r < 4; ++r)
                op[(size_t)(r0 + kq * 4 + r) * NH + j * 16 + mlow] = (__bf16)acc[2ull*0 + w][j][r];
    }
    // V -> LDS transposed
    #pragma unroll
    for (int j = 0; j < 6; ++j)
        #pragma unroll
        for (int r = 0; r < 4; ++r)
            VsT[j * 16 + mlow][wave * 16 + kq * 4 + r] = (__bf16)acc[2][j][r];
    __syncthreads();
    // coalesced transposed store: 96 cols x 64 rows, 8-elem chunks
    #pragma unroll
    for (int it = 0; it < 3; ++it) {
        int idx = it * 256 + threadIdx.x;   // 0..767
        int c = idx >> 3, g = idx & 7;
        *(v8bf*)(vt + (size_t)c * MROWS + m0 + g * 8) = *(const v8bf*)&VsT[c][g * 8];
    }
}

// ---------------------------------------------------------------------------
// MFMA causal flash attention. Barrier-free.
// Block = 4 waves, Q-tile 64 (16 rows/wave, Q frags in registers).
// KV tile 64: S = 12 MFMA (K frags straight from global bf16 row-major),
// softmax in C-layout regs, P -> per-wave LDS -> A-frags, PV = 12 MFMA
// (V frags straight from global vt[96][32768]).
// ---------------------------------------------------------------------------
__global__ __launch_bounds__(256) void attn_mfma(
    const __bf16* __restrict__ qk,
    const __bf16* __restrict__ vt,
    float* __restrict__ out)
{
    __shared__ __bf16 Ps[4][16][72];   // per-wave P tile, stride 72 (bank-spread)

    const int bid = blockIdx.x;
    const int b   = bid & 15;
    const int rr_ = bid >> 4;                                 // 0..31
    const int qt  = (rr_ < 16) ? (2 * rr_) : (63 - 2 * rr_);  // balance swizzle
    const int q0  = qt * 64;

    const int wave = threadIdx.x >> 6;
    const int lane = threadIdx.x & 63;
    const int mlow = lane & 15;
    const int kq   = lane >> 4;

    const __bf16* qp  = qk + (size_t)b * SEQLEN * NH;
    const __bf16* kp  = qk + (size_t)MROWS * NH + (size_t)b * SEQLEN * NH;
    const __bf16* vtp = vt + (size_t)b * SEQLEN;

    // Q fragments (A layout: m=lane&15, k=(lane>>4)*8+j), 3 slices of 32
    const int qrow = q0 + wave * 16 + mlow;
    v8bf qa[3];
    #pragma unroll
    for (int s = 0; s < 3; ++s)
        qa[s] = *(const v8bf*)(qp + (size_t)qrow * NH + s * 32 + kq * 8);

    float m_run[4], l_run[4];
    v4f O[6];
    #pragma unroll
    for (int r = 0; r < 4; ++r) { m_run[r] = -INFINITY; l_run[r] = 0.0f; }
    #pragma unroll
    for (int j = 0; j < 6; ++j) O[j] = (v4f)0.0f;

    const float sscale = 0.10206207261596575f * 1.4426950408889634f;

    for (int t = 0; t <= qt; ++t) {
        const int k0 = t * 64;
        const bool diag = (t == qt);
        const int t4max = diag ? wave : 3;   // wave-uniform causal skip

        float s2[4][4];                      // [t4][r]
        #pragma unroll
        for (int t4 = 0; t4 < 4; ++t4)
            #pragma unroll
            for (int r = 0; r < 4; ++r) s2[t4][r] = -1e20f;

        for (int t4 = 0; t4 <= t4max; ++t4) {
            v4f sa = (v4f)0.0f;
            const __bf16* kr = kp + (size_t)(k0 + t4 * 16 + mlow) * NH + kq * 8;
            #pragma unroll
            for (int s = 0; s < 3; ++s) {
                v8bf kb = *(const v8bf*)(kr + s * 32);
                sa = __builtin_amdgcn_mfma_f32_16x16x32_bf16(qa[s], kb, sa, 0, 0, 0);
            }
            #pragma unroll
            for (int r = 0; r < 4; ++r) s2[t4][r] = sa[r] * sscale;
        }
        if (diag) {
            // mask within diagonal 16x16: key rel = mlow, query rel = kq*4+r
            #pragma unroll
            for (int r = 0; r < 4; ++r)
                if (mlow > kq * 4 + r) s2[wave][r] = -1e20f;
        }

        // online softmax (rows = kq*4+r; 16 lanes per row-group)
        float mt[4];
        #pragma unroll
        for (int r = 0; r < 4; ++r)
            mt[r] = fmaxf(fmaxf(s2[0][r], s2[1][r]), fmaxf(s2[2][r], s2[3][r]));
        #pragma unroll
        for (int off = 1; off < 16; off <<= 1)
            #pragma unroll
            for (int r = 0; r < 4; ++r)
                mt[r] = fmaxf(mt[r], __shfl_xor(mt[r], off));

        float alpha[4];
        #pragma unroll
        for (int r = 0; r < 4; ++r) {
            float mn = fmaxf(m_run[r], mt[r]);
            alpha[r] = exp2f(m_run[r] - mn);
            m_run[r] = mn;
        }

        float p[4][4], rs[4];
        #pragma unroll
        for (int r = 0; r < 4; ++r) rs[r] = 0.0f;
        #pragma unroll
        for (int t4 = 0; t4 < 4; ++t4)
            #pragma unroll
            for (int r = 0; r < 4; ++r) {
                p[t4][r] = exp2f(s2[t4][r] - m_run[r]);
                rs[r] += p[t4][r];
            }
        #pragma unroll
        for (int off = 1; off < 16; off <<= 1)
            #pragma unroll
            for (int r = 0; r < 4; ++r)
                rs[r] += __shfl_xor(rs[r], off);
        #pragma unroll
        for (int r = 0; r < 4; ++r)
            l_run[r] = l_run[r] * alpha[r] + rs[r];
        #pragma unroll
        for (int j = 0; j < 6; ++j) {
            v4f a4; a4[0]=alpha[0]; a4[1]=alpha[1]; a4[2]=alpha[2]; a4[3]=alpha[3];
            O[j] *= a4;
        }

        // P: C layout -> LDS -> A layout (per-wave region, no barrier)
        #pragma unroll
        for (int t4 = 0; t4 < 4; ++t4)
            #pragma unroll
            for (int r = 0; r < 4; ++r)
                Ps[wave][kq * 4 + r][t4 * 16 + mlow] = (__bf16)p[t4][r];

        v8bf pa0 = *(const v8bf*)&Ps[wave][mlow][kq * 8];
        v8bf pa1 = *(const v8bf*)&Ps[wave][mlow][32 + kq * 8];

        const __bf16* vr = vtp + k0 + kq * 8;
        #pragma unroll
        for (int j = 0; j < 6; ++j) {
            v8bf vb0 = *(const v8bf*)(vr + (size_t)(j * 16 + mlow) * MROWS);
            v8bf vb1 = *(const v8bf*)(vr + (size_t)(j * 16 + mlow) * MROWS + 32);
            O[j] = __builtin_amdgcn_mfma_f32_16x16x32_bf16(pa0, vb0, O[j], 0, 0, 0);
            O[j] = __builtin_amdgcn_mfma_f32_16x16x32_bf16(pa1, vb1, O[j], 0, 0, 0);
        }
    }

    // epilogue: normalize, store fp32
    float inv[4];
    #pragma unroll
    for (int r = 0; r < 4; ++r) inv[r] = 1.0f / l_run[r];
    #pragma unroll
    for (int r = 0; r < 4; ++r) {
        float* orow = out + ((size_t)b * SEQLEN + q0 + wave * 16 + kq * 4 + r) * NH;
        #pragma unroll
        for (int j = 0; j < 6; ++j)
            orow[j * 16 + mlow] = O[j][r] * inv[r];
    }
}

// ---------------------------------------------------------------------------
extern "C" void kernel_launch(void* const* d_in, const int* in_sizes, int n_in,
                              void* d_out, int out_size, void* d_ws, size_t ws_size,
                              hipStream_t stream)
{
    (void)in_sizes; (void)n_in; (void)out_size; (void)ws_size;
    const float* x  = (const float*)d_in[0];
    const float* Wq = (const float*)d_in[1];
    const float* Wk = (const float*)d_in[2];
    const float* Wv = (const float*)d_in[3];
    float* out = (float*)d_out;

    __bf16* qk = (__bf16*)d_ws;                                   // 12.58 MB (Q,K)
    __bf16* vt = qk + (size_t)2 * MROWS * NH;                     //  6.29 MB (V^T)
    __bf16* Wp = vt + (size_t)NH * MROWS;                         //  0.44 MB

    pack_w<<<(3 * 24 * 6 * 64 + 255) / 256, 256, 0, stream>>>(Wq, Wk, Wv, Wp);
    qkv_fused<<<MROWS / 64, 256, 0, stream>>>(x, Wp, qk, vt);
    attn_mfma<<<dim3(512), 256, 0, stream>>>(qk, vt, out);
}

// Round 4
// 309.089 us; speedup vs baseline: 5.1548x; 1.2851x over previous
//
#include <hip/hip_runtime.h>
#include <math.h>

#define EMB_K   768
#define NH      96
#define SEQLEN  2048
#define NBATCH  16
#define MROWS   (NBATCH * SEQLEN)   // 32768

typedef __bf16 v8bf __attribute__((ext_vector_type(8)));
typedef float  v4f  __attribute__((ext_vector_type(4)));

// ---------------------------------------------------------------------------
// Pack Wq/Wk/Wv (fp32 [768][96]) into bf16 B-fragment order for
// mfma_f32_16x16x32_bf16:  B[k][n], n = lane&15, k = (lane>>4)*8 + e.
// Frag (w, s, j) at ((w*24 + s)*6 + j)*512 + lane*8 + e  (bf16 units)
// ---------------------------------------------------------------------------
__global__ __launch_bounds__(256) void pack_w(
    const float* __restrict__ Wq,
    const float* __restrict__ Wk,
    const float* __restrict__ Wv,
    __bf16* __restrict__ Wp)
{
    int t = blockIdx.x * 256 + threadIdx.x;
    if (t >= 3 * 24 * 6 * 64) return;
    int l  = t & 63;
    int fj = (t >> 6) % 6;
    int s  = ((t >> 6) / 6) % 24;
    int w  = (t >> 6) / (6 * 24);
    const float* W = (w == 0) ? Wq : ((w == 1) ? Wk : Wv);
    int n     = fj * 16 + (l & 15);
    int kbase = s * 32 + (l >> 4) * 8;
    __bf16 o[8];
    #pragma unroll
    for (int e = 0; e < 8; ++e)
        o[e] = (__bf16)W[(size_t)(kbase + e) * NH + n];
    *(v8bf*)(Wp + (size_t)t * 8) = *(v8bf*)o;
}

__device__ inline v8bf cvt8(const float4& a, const float4& b)
{
    v8bf r;
    r[0] = (__bf16)a.x; r[1] = (__bf16)a.y; r[2] = (__bf16)a.z; r[3] = (__bf16)a.w;
    r[4] = (__bf16)b.x; r[5] = (__bf16)b.y; r[6] = (__bf16)b.z; r[7] = (__bf16)b.w;
    return r;
}

// ---------------------------------------------------------------------------
// Fused QKV, split-K. Block = 512 thr = 8 waves = 4 row-tiles x 2 K-halves.
// Each wave: 16 rows x 12 K-slices, 18 MFMA/slice. Partial accs combined in
// LDS (3 rounds), even waves do the epilogue. 4096 waves total (16/CU).
// ---------------------------------------------------------------------------
__global__ __launch_bounds__(512, 4) void qkv_fused(
    const float* __restrict__ x,
    const __bf16* __restrict__ Wp,
    __bf16* __restrict__ qk,
    __bf16* __restrict__ vt)
{
    __shared__ float  Cs[4][64][25];   // stride 25: conflict-free
    __shared__ __bf16 VsT[96][72];

    const int wave = threadIdx.x >> 6;   // 0..7
    const int p    = wave >> 1;          // row-tile 0..3
    const int h    = wave & 1;           // K-half
    const int lane = threadIdx.x & 63;
    const int mlow = lane & 15;
    const int kq   = lane >> 4;
    const int m0   = blockIdx.x * 64;
    const int r0   = m0 + p * 16;

    const float* xr = x + (size_t)(r0 + mlow) * EMB_K + h * 384 + kq * 8;
    const __bf16* bp = Wp + (size_t)lane * 8;

    v4f acc[3][6];
    #pragma unroll
    for (int w = 0; w < 3; ++w)
        #pragma unroll
        for (int j = 0; j < 6; ++j)
            acc[w][j] = (v4f)0.0f;

    #pragma unroll
    for (int s = 0; s < 12; ++s) {
        float4 lo = *(const float4*)(xr + s * 32);
        float4 hi = *(const float4*)(xr + s * 32 + 4);
        v8bf a = cvt8(lo, hi);
        const int sg = h * 12 + s;
        #pragma unroll
        for (int w = 0; w < 3; ++w)
            #pragma unroll
            for (int j = 0; j < 6; ++j) {
                v8bf bf = *(const v8bf*)(bp + ((size_t)(w * 24 + sg) * 6 + j) * 512);
                acc[w][j] = __builtin_amdgcn_mfma_f32_16x16x32_bf16(a, bf, acc[w][j], 0, 0, 0);
            }
    }

    // combine the two K-halves through LDS, one w at a time
    #pragma unroll
    for (int w = 0; w < 3; ++w) {
        if (h == 1) {
            #pragma unroll
            for (int j = 0; j < 6; ++j)
                #pragma unroll
                for (int r = 0; r < 4; ++r)
                    Cs[p][lane][j * 4 + r] = acc[w][j][r];
        }
        __syncthreads();
        if (h == 0) {
            #pragma unroll
            for (int j = 0; j < 6; ++j)
                #pragma unroll
                for (int r = 0; r < 4; ++r)
                    acc[w][j][r] += Cs[p][lane][j * 4 + r];
        }
        __syncthreads();
    }

    if (h == 0) {
        // Q, K: bf16 row-major.  C layout: row=(lane>>4)*4+r, col=lane&15.
        #pragma unroll
        for (int w = 0; w < 2; ++w) {
            __bf16* op = qk + (size_t)w * MROWS * NH;
            #pragma unroll
            for (int j = 0; j < 6; ++j)
                #pragma unroll
                for (int r = 0; r < 4; ++r)
                    op[(size_t)(r0 + kq * 4 + r) * NH + j * 16 + mlow] = (__bf16)acc[w][j][r];
        }
        // V -> LDS transposed
        #pragma unroll
        for (int j = 0; j < 6; ++j)
            #pragma unroll
            for (int r = 0; r < 4; ++r)
                VsT[j * 16 + mlow][p * 16 + kq * 4 + r] = (__bf16)acc[2][j][r];
    }
    __syncthreads();
    // coalesced transposed V store: 96 cols x 64 rows in 8-elem chunks
    #pragma unroll
    for (int it = 0; it < 2; ++it) {
        int idx = it * 512 + threadIdx.x;   // 0..1023, need 768
        if (idx < 768) {
            int c = idx >> 3, g = idx & 7;
            *(v8bf*)(vt + (size_t)c * MROWS + m0 + g * 8) = *(const v8bf*)&VsT[c][g * 8];
        }
    }
}

// ---------------------------------------------------------------------------
// MFMA causal flash attention, split-KV. Barrier-free.
// Block = 4 waves, Q-tile 64. KV chunk = up to 16 KV-tiles of 64 keys.
// qt<16: single chunk -> write out directly. qt>=16: two chunks write
// normalized partial O + (m,l) to ws; attn_combine merges.
// Heavy blocks dispatched first (low blockIdx).
// ---------------------------------------------------------------------------
__global__ __launch_bounds__(256) void attn_mfma(
    const __bf16* __restrict__ qk,
    const __bf16* __restrict__ vt,
    float* __restrict__ out,
    float* __restrict__ Opart,
    float* __restrict__ ml)
{
    __shared__ __bf16 Ps[4][16][72];   // per-wave P tile

    const int bid = blockIdx.x;
    const int b   = bid & 15;
    const int j   = bid >> 4;          // 0..47
    int qt, c0, nch;
    if (j < 16)      { qt = 16 + j;  c0 = 0; nch = 2; }   // heavy, no diagonal
    else if (j < 32) { qt = 47 - j;  c0 = 1; nch = 2; }   // diagonal chunks
    else             { qt = 47 - j;  c0 = 0; nch = 1; }   // qt<16, full range
    const int t0 = c0 * 16;
    const int t1 = (t0 + 16 < qt + 1) ? (t0 + 16) : (qt + 1);
    const int q0 = qt * 64;

    const int wave = threadIdx.x >> 6;
    const int lane = threadIdx.x & 63;
    const int mlow = lane & 15;
    const int kq   = lane >> 4;

    const __bf16* qp  = qk + (size_t)b * SEQLEN * NH;
    const __bf16* kp  = qk + (size_t)MROWS * NH + (size_t)b * SEQLEN * NH;
    const __bf16* vtp = vt + (size_t)b * SEQLEN;

    // Q fragments (A layout: m=lane&15, k=(lane>>4)*8+j)
    const int qrow = q0 + wave * 16 + mlow;
    v8bf qa[3];
    #pragma unroll
    for (int s = 0; s < 3; ++s)
        qa[s] = *(const v8bf*)(qp + (size_t)qrow * NH + s * 32 + kq * 8);

    float m_run[4], l_run[4];
    v4f O[6];
    #pragma unroll
    for (int r = 0; r < 4; ++r) { m_run[r] = -INFINITY; l_run[r] = 0.0f; }
    #pragma unroll
    for (int jj = 0; jj < 6; ++jj) O[jj] = (v4f)0.0f;

    const float sscale = 0.10206207261596575f * 1.4426950408889634f;

    // prefetch first tile's t4=0 K trio
    v8bf k0f[3];
    {
        const __bf16* kr = kp + (size_t)(t0 * 64 + mlow) * NH + kq * 8;
        #pragma unroll
        for (int s = 0; s < 3; ++s) k0f[s] = *(const v8bf*)(kr + s * 32);
    }

    for (int t = t0; t < t1; ++t) {
        const int k0 = t * 64;
        const bool diag = (t == qt);
        const int t4max = diag ? wave : 3;

        float s2[4][4];
        #pragma unroll
        for (int t4 = 0; t4 < 4; ++t4)
            #pragma unroll
            for (int r = 0; r < 4; ++r) s2[t4][r] = -1e20f;

        {   // t4 = 0 from prefetched regs
            v4f sa = (v4f)0.0f;
            #pragma unroll
            for (int s = 0; s < 3; ++s)
                sa = __builtin_amdgcn_mfma_f32_16x16x32_bf16(qa[s], k0f[s], sa, 0, 0, 0);
            #pragma unroll
            for (int r = 0; r < 4; ++r) s2[0][r] = sa[r] * sscale;
        }
        for (int t4 = 1; t4 <= t4max; ++t4) {
            v4f sa = (v4f)0.0f;
            const __bf16* kr = kp + (size_t)(k0 + t4 * 16 + mlow) * NH + kq * 8;
            #pragma unroll
            for (int s = 0; s < 3; ++s) {
                v8bf kb = *(const v8bf*)(kr + s * 32);
                sa = __builtin_amdgcn_mfma_f32_16x16x32_bf16(qa[s], kb, sa, 0, 0, 0);
            }
            #pragma unroll
            for (int r = 0; r < 4; ++r) s2[t4][r] = sa[r] * sscale;
        }
        // prefetch next tile's t4=0 trio (overlaps softmax + PV)
        if (t + 1 < t1) {
            const __bf16* kr = kp + (size_t)((t + 1) * 64 + mlow) * NH + kq * 8;
            #pragma unroll
            for (int s = 0; s < 3; ++s) k0f[s] = *(const v8bf*)(kr + s * 32);
        }
        if (diag) {
            #pragma unroll
            for (int r = 0; r < 4; ++r)
                if (mlow > kq * 4 + r) s2[wave][r] = -1e20f;
        }

        // online softmax (row r lives on the 16 lanes sharing kq; row=kq*4+r)
        float mt[4];
        #pragma unroll
        for (int r = 0; r < 4; ++r)
            mt[r] = fmaxf(fmaxf(s2[0][r], s2[1][r]), fmaxf(s2[2][r], s2[3][r]));
        #pragma unroll
        for (int off = 1; off < 16; off <<= 1)
            #pragma unroll
            for (int r = 0; r < 4; ++r)
                mt[r] = fmaxf(mt[r], __shfl_xor(mt[r], off));

        float alpha[4];
        #pragma unroll
        for (int r = 0; r < 4; ++r) {
            float mn = fmaxf(m_run[r], mt[r]);
            alpha[r] = exp2f(m_run[r] - mn);
            m_run[r] = mn;
        }

        float pv[4][4], rs[4];
        #pragma unroll
        for (int r = 0; r < 4; ++r) rs[r] = 0.0f;
        #pragma unroll
        for (int t4 = 0; t4 < 4; ++t4)
            #pragma unroll
            for (int r = 0; r < 4; ++r) {
                pv[t4][r] = exp2f(s2[t4][r] - m_run[r]);
                rs[r] += pv[t4][r];
            }
        #pragma unroll
        for (int off = 1; off < 16; off <<= 1)
            #pragma unroll
            for (int r = 0; r < 4; ++r)
                rs[r] += __shfl_xor(rs[r], off);
        #pragma unroll
        for (int r = 0; r < 4; ++r)
            l_run[r] = l_run[r] * alpha[r] + rs[r];
        #pragma unroll
        for (int jj = 0; jj < 6; ++jj) {
            v4f a4; a4[0]=alpha[0]; a4[1]=alpha[1]; a4[2]=alpha[2]; a4[3]=alpha[3];
            O[jj] *= a4;
        }

        // P: C layout -> per-wave LDS -> A layout
        #pragma unroll
        for (int t4 = 0; t4 < 4; ++t4)
            #pragma unroll
            for (int r = 0; r < 4; ++r)
                Ps[wave][kq * 4 + r][t4 * 16 + mlow] = (__bf16)pv[t4][r];

        v8bf pa0 = *(const v8bf*)&Ps[wave][mlow][kq * 8];
        v8bf pa1 = *(const v8bf*)&Ps[wave][mlow][32 + kq * 8];

        const __bf16* vr = vtp + k0 + kq * 8;
        #pragma unroll
        for (int jj = 0; jj < 6; ++jj) {
            v8bf vb0 = *(const v8bf*)(vr + (size_t)(jj * 16 + mlow) * MROWS);
            v8bf vb1 = *(const v8bf*)(vr + (size_t)(jj * 16 + mlow) * MROWS + 32);
            O[jj] = __builtin_amdgcn_mfma_f32_16x16x32_bf16(pa0, vb0, O[jj], 0, 0, 0);
            O[jj] = __builtin_amdgcn_mfma_f32_16x16x32_bf16(pa1, vb1, O[jj], 0, 0, 0);
        }
    }

    float inv[4];
    #pragma unroll
    for (int r = 0; r < 4; ++r) inv[r] = 1.0f / l_run[r];

    if (nch == 1) {
        #pragma unroll
        for (int r = 0; r < 4; ++r) {
            float* orow = out + ((size_t)b * SEQLEN + q0 + wave * 16 + kq * 4 + r) * NH;
            #pragma unroll
            for (int jj = 0; jj < 6; ++jj)
                orow[jj * 16 + mlow] = O[jj][r] * inv[r];
        }
    } else {
        const int e = (b * 16 + (qt - 16)) * 2 + c0;
        float* Pp = Opart + (size_t)e * 64 * 96;
        #pragma unroll
        for (int r = 0; r < 4; ++r) {
            int row = wave * 16 + kq * 4 + r;
            #pragma unroll
            for (int jj = 0; jj < 6; ++jj)
                Pp[row * 96 + jj * 16 + mlow] = O[jj][r] * inv[r];
            if (mlow == 0) {
                ml[(size_t)e * 128 + row * 2]     = m_run[r];
                ml[(size_t)e * 128 + row * 2 + 1] = l_run[r];
            }
        }
    }
}

// ---------------------------------------------------------------------------
// Merge the two partials for qt>=16 rows. One block per (b, qt).
// ---------------------------------------------------------------------------
__global__ __launch_bounds__(256) void attn_combine(
    const float* __restrict__ Opart,
    const float* __restrict__ ml,
    float* __restrict__ out)
{
    __shared__ float c0s[64], c1s[64];
    const int b  = blockIdx.x & 15;
    const int qr = blockIdx.x >> 4;       // 0..15 -> qt = 16+qr
    const int e0 = (b * 16 + qr) * 2;
    const int tid = threadIdx.x;
    if (tid < 64) {
        float m0 = ml[(size_t)e0 * 128 + tid * 2];
        float l0 = ml[(size_t)e0 * 128 + tid * 2 + 1];
        float m1 = ml[(size_t)(e0 + 1) * 128 + tid * 2];
        float l1 = ml[(size_t)(e0 + 1) * 128 + tid * 2 + 1];
        float M  = fmaxf(m0, m1);
        float a0 = exp2f(m0 - M) * l0;
        float a1 = exp2f(m1 - M) * l1;
        float inv = 1.0f / (a0 + a1);
        c0s[tid] = a0 * inv;
        c1s[tid] = a1 * inv;
    }
    __syncthreads();
    const float4* P0 = (const float4*)(Opart + (size_t)e0 * 64 * 96);
    const float4* P1 = (const float4*)(Opart + (size_t)(e0 + 1) * 64 * 96);
    float4* op = (float4*)(out + ((size_t)b * SEQLEN + (16 + qr) * 64) * NH);
    #pragma unroll
    for (int it = 0; it < 6; ++it) {
        int idx = it * 256 + tid;          // 0..1535
        int row = idx / 24;
        float4 a = P0[idx], c = P1[idx];
        float w0 = c0s[row], w1 = c1s[row];
        float4 o;
        o.x = w0 * a.x + w1 * c.x;
        o.y = w0 * a.y + w1 * c.y;
        o.z = w0 * a.z + w1 * c.z;
        o.w = w0 * a.w + w1 * c.w;
        op[idx] = o;
    }
}

// ---------------------------------------------------------------------------
extern "C" void kernel_launch(void* const* d_in, const int* in_sizes, int n_in,
                              void* d_out, int out_size, void* d_ws, size_t ws_size,
                              hipStream_t stream)
{
    (void)in_sizes; (void)n_in; (void)out_size; (void)ws_size;
    const float* x  = (const float*)d_in[0];
    const float* Wq = (const float*)d_in[1];
    const float* Wk = (const float*)d_in[2];
    const float* Wv = (const float*)d_in[3];
    float* out = (float*)d_out;

    __bf16* qk = (__bf16*)d_ws;                                   // 12.58 MB
    __bf16* vt = qk + (size_t)2 * MROWS * NH;                     //  6.29 MB
    __bf16* Wp = vt + (size_t)NH * MROWS;                         //  0.44 MB
    float* Opart = (float*)(Wp + (size_t)3 * 24 * 6 * 512);       // 12.58 MB
    float* ml    = Opart + (size_t)512 * 64 * 96;                 //  0.26 MB

    pack_w<<<(3 * 24 * 6 * 64 + 255) / 256, 256, 0, stream>>>(Wq, Wk, Wv, Wp);
    qkv_fused<<<MROWS / 64, 512, 0, stream>>>(x, Wp, qk, vt);
    attn_mfma<<<dim3(768), 256, 0, stream>>>(qk, vt, out, Opart, ml);
    attn_combine<<<dim3(256), 256, 0, stream>>>(Opart, ml, out);
}